// Round 1
// baseline (101.313 us; speedup 1.0000x reference)
//
#include <hip/hip_runtime.h>
#include <hip/hip_bf16.h>

namespace {

constexpr int D = 4096;
constexpr int NT = 256;

// Additive LDS pad: +4 dwords per 32 → addr(i) = i + 4*(i>>5). Bijective
// (strictly increasing), keeps 16-aligned runs contiguous (for b128 ops),
// spreads banks for the strided access rounds.
__device__ __forceinline__ void fwht16(float v[16]) {
#pragma unroll
    for (int h = 1; h < 16; h <<= 1) {
#pragma unroll
        for (int g = 0; g < 16; g += (h << 1)) {
#pragma unroll
            for (int j = 0; j < h; ++j) {
                const float a = v[g + j];
                const float b = v[g + j + h];
                v[g + j] = a + b;
                v[g + j + h] = a - b;
            }
        }
    }
}

__global__ __launch_bounds__(NT) void rht_kernel(const float* __restrict__ x,
                                                 const float* __restrict__ signs,
                                                 float* __restrict__ out) {
    __shared__ float lds[D + (D >> 5) * 4];  // 4608 floats = 18 KiB
    const int t = threadIdx.x;
    const size_t row = blockIdx.x;
    const float* __restrict__ xr = x + row * (size_t)D;
    float* __restrict__ outr = out + row * (size_t)D;

    float v[16];

    // ---- Round 1: thread owns i = 16t + k  → butterflies on index bits 0-3.
    // Vectorized 16B/lane loads; wave's 4 loads cover a contiguous 4 KiB span.
    {
        const float4* __restrict__ x4 = reinterpret_cast<const float4*>(xr) + (t << 2);
        const float4* __restrict__ s4 = reinterpret_cast<const float4*>(signs) + (t << 2);
#pragma unroll
        for (int q = 0; q < 4; ++q) {
            const float4 a = x4[q];
            const float4 s = s4[q];
            v[4 * q + 0] = a.x * s.x;
            v[4 * q + 1] = a.y * s.y;
            v[4 * q + 2] = a.z * s.z;
            v[4 * q + 3] = a.w * s.w;
        }
    }
    fwht16(v);
    {
        // padded addr of i = 16t+k: base = 16t + 4*(t>>1), contiguous 16 dwords
        float* p = &lds[(t << 4) + ((t >> 1) << 2)];
#pragma unroll
        for (int q = 0; q < 4; ++q)
            reinterpret_cast<float4*>(p)[q] =
                make_float4(v[4 * q], v[4 * q + 1], v[4 * q + 2], v[4 * q + 3]);
    }
    __syncthreads();

    // ---- Round 2: thread owns i = (t>>4)*256 + 16k + (t&15) → bits 4-7.
    // padded addr = 288*(t>>4) + 16k + 4*(k>>1) + (t&15)
    // Each element is read+written by exactly one thread → no barrier between
    // the read and the write-back inside this round.
    {
        const int b2 = (t >> 4) * 288 + (t & 15);
#pragma unroll
        for (int k = 0; k < 16; ++k) v[k] = lds[b2 + (k << 4) + ((k >> 1) << 2)];
        fwht16(v);
#pragma unroll
        for (int k = 0; k < 16; ++k) lds[b2 + (k << 4) + ((k >> 1) << 2)] = v[k];
    }
    __syncthreads();

    // ---- Round 3: thread owns i = 256k + t → bits 8-11.
    // padded addr = 288k + t + 4*(t>>5). Stores are perfectly coalesced dwords.
    {
        const int b3 = t + ((t >> 5) << 2);
#pragma unroll
        for (int k = 0; k < 16; ++k) v[k] = lds[b3 + 288 * k];
        fwht16(v);
#pragma unroll
        for (int k = 0; k < 16; ++k) outr[(k << 8) + t] = v[k] * 0.015625f;  // 1/sqrt(4096)
    }
}

}  // namespace

extern "C" void kernel_launch(void* const* d_in, const int* in_sizes, int n_in,
                              void* d_out, int out_size, void* d_ws, size_t ws_size,
                              hipStream_t stream) {
    const float* x = (const float*)d_in[0];
    const float* signs = (const float*)d_in[1];
    float* out = (float*)d_out;
    const int B = in_sizes[0] / D;  // 16384 rows
    rht_kernel<<<dim3(B), dim3(NT), 0, stream>>>(x, signs, out);
}